// Round 1
// 1131.722 us; speedup vs baseline: 2.2411x; 2.2411x over previous
//
#include <hip/hip_runtime.h>
#include <math.h>

#define B_    32
#define T_    21
#define STEPS 20
#define V_    10000
#define E_    512
#define A_    512
#define L_    512
#define P_    196
#define ENC_  2048
#define XW_   3072   // bf16 X' row: [emb(512) | awe*beta(2048) | h(512)]
#define NT2_  792    // GEMM2 n-tiles of 16 (12672 cols: Wb 2048 | Wga 512 | Wo 10000 | pad 112)
#define N2_   12672

// ---- workspace layout (float offsets), total 9,551,936 fl = 38.2 MB ----
#define WS_ORD    0
#define WS_SLEN   32
#define WS_CBUF   64        // 2*16384 fp32 c double-buffer
#define WS_CB     32832     // bf16 32*512   -> 8192 fl
#define WS_XB     41024     // bf16 32*3072  -> 49152 fl
#define WS_A2S    90176     // 32*512
#define WS_ESH    106560    // 32*256
#define WS_BETA   114752    // 32*2048
#define WS_PZ4    180288    // 4*32*2048
#define WS_A1B    442432    // bf16 6272*512 -> 1605632 fl
#define WS_WZP    2048064   // bf16 128nt*96kt*64*8 -> 3145728 fl
#define WS_WCP    5193792   // bf16 792nt*16kt*64*8 -> 3244032 fl
#define WS_MEAN   8437824   // 32*2048 (prologue only)
#define WS_PH     8503360   // 32*32*512 (prologue only)
#define WS_WEAT   9027648   // bf16 512*2048 -> 524288 fl (prologue only)

// ---- output layout (float offsets) ----
#define OUT_PRED  0
#define OUT_ALPHA 6400000
#define OUT_ORDER 6525440

typedef __attribute__((ext_vector_type(8))) short bf16x8;
typedef __attribute__((ext_vector_type(4))) float f32x4;
typedef unsigned short ushort_t;

__device__ inline unsigned f2bf2(float lo, float hi) {
    unsigned a = __float_as_uint(lo), b = __float_as_uint(hi);
    a = (a + 0x7FFFu + ((a >> 16) & 1u)) >> 16;
    b = (b + 0x7FFFu + ((b >> 16) & 1u)) >> 16;
    return a | (b << 16);
}
__device__ inline ushort_t f2bf(float f) {
    unsigned u = __float_as_uint(f);
    return (ushort_t)((u + 0x7FFFu + ((u >> 16) & 1u)) >> 16);
}
__device__ inline float bfu_lo(unsigned u) { return __uint_as_float(u << 16); }
__device__ inline float bfu_hi(unsigned u) { return __uint_as_float(u & 0xFFFF0000u); }

// ============ order / lengths ============
__global__ void k_order(const int* __restrict__ seqs, int* __restrict__ ord,
                        int* __restrict__ slen, float* __restrict__ out_ord)
{
    __shared__ int len[B_];
    int i = threadIdx.x;
    if (i < B_) {
        int c = 0;
        for (int t = 0; t < T_; ++t) c += (seqs[i * T_ + t] != 0) ? 1 : 0;
        len[i] = c;
    }
    __syncthreads();
    if (i < B_) {
        int li = len[i], r = 0;
        for (int j = 0; j < B_; ++j) {
            int lj = len[j];
            if (lj > li || (lj == li && j < i)) ++r;
        }
        ord[r] = i; slen[r] = li - 1; out_ord[r] = (float)i;
    }
}

// ============ mean-pool encoder (sorted) ============
__global__ void k_mean(const float* __restrict__ enc, const int* __restrict__ ord,
                       float* __restrict__ mean)
{
    int tid = blockIdx.x * 256 + threadIdx.x;
    int b = tid >> 11, e = tid & 2047;
    const float* row = enc + (size_t)ord[b] * (P_ * ENC_) + e;
    float s = 0.f;
    for (int p = 0; p < P_; ++p) s += row[(size_t)p * ENC_];
    mean[tid] = s * (1.0f / 196.0f);
}

// ============ cast + transpose Wea -> WeaT bf16 [512][2048] ============
__global__ void k_castWT(const float* __restrict__ Wea, ushort_t* __restrict__ WT)
{
    int tid = blockIdx.x * 256 + threadIdx.x;
    int n = tid >> 11, k = tid & 2047;
    WT[tid] = f2bf(Wea[(size_t)k * 512 + n]);
}

// ============ prologue skinny GEMM partial (fp32) for h0/c0 ============
__global__ void sg_partial(const float* __restrict__ X, const float* __restrict__ W,
                           float* __restrict__ part, int K, int N, int kchunk, int chunk_ofs)
{
    const int n = blockIdx.x * 256 + threadIdx.x;
    const int c = blockIdx.y;
    const int bh = blockIdx.z;
    const int k0 = c * kchunk;
    int k1 = k0 + kchunk; if (k1 > K) k1 = K;
    float acc[16];
#pragma unroll
    for (int b = 0; b < 16; ++b) acc[b] = 0.f;
    if (n < N) {
        const float* Xb = X + (size_t)(bh * 16) * K;
        for (int k = k0; k < k1; k += 4) {
            float w0 = W[(size_t)(k + 0) * N + n];
            float w1 = W[(size_t)(k + 1) * N + n];
            float w2 = W[(size_t)(k + 2) * N + n];
            float w3 = W[(size_t)(k + 3) * N + n];
#pragma unroll
            for (int b = 0; b < 16; ++b) {
                const float4 xv = *reinterpret_cast<const float4*>(&Xb[(size_t)b * K + k]);
                acc[b] += xv.x * w0 + xv.y * w1 + xv.z * w2 + xv.w * w3;
            }
        }
        float* po = part + (size_t)(chunk_ofs + c) * (B_ * (size_t)N) + (size_t)(bh * 16) * N;
#pragma unroll
        for (int b = 0; b < 16; ++b) po[(size_t)b * N + n] = acc[b];
    }
}

// ============ h0/c0 combine: c0 fp32 + cB bf16 + h0 into XB h-section ============
__global__ void k_h0c0(const float* __restrict__ ph, const float* __restrict__ bim,
                       const float* __restrict__ bic, float* __restrict__ c0,
                       ushort_t* __restrict__ cB, ushort_t* __restrict__ XB)
{
    int tid = blockIdx.x * 256 + threadIdx.x;
    int half = tid >> 14;
    int idx = tid & 16383;
    int l = idx & 511, b = idx >> 9;
    int cofs = half ? 16 : 0;
    float s = 0.f;
    for (int c = 0; c < 16; ++c) s += ph[(size_t)(cofs + c) * (B_ * 512) + idx];
    if (half) {
        float cv = s + bic[l];
        c0[idx] = cv;
        cB[idx] = f2bf(cv);
    } else {
        XB[(size_t)b * XW_ + 2560 + l] = f2bf(s + bim[l]);
    }
}

// ============ a1 MFMA, double-buffered LDS pipeline (unchanged, verified) ============
__global__ __launch_bounds__(256, 1) void k_a1_mfma(
    const float* __restrict__ enc, const ushort_t* __restrict__ WeaT,
    const float* __restrict__ bea, const int* __restrict__ ord,
    ushort_t* __restrict__ a1b)
{
    __shared__ ushort_t As[2][128 * 40];
    __shared__ ushort_t Bs[2][128 * 40];
    const int tid = threadIdx.x;
    const int lane = tid & 63, wave = tid >> 6;
    const int m0 = blockIdx.x * 128;
    const int n0 = blockIdx.y * 128;

    const int c0 = tid, c1 = tid + 256;
    const int ar0 = c0 >> 2, ak0 = (c0 & 3) * 8;
    const int ar1 = c1 >> 2, ak1 = (c1 & 3) * 8;
    const int g0 = m0 + ar0, g1 = m0 + ar1;
    const float* Ag0 = enc + ((size_t)ord[g0 / P_] * P_ + (g0 % P_)) * ENC_ + ak0;
    const float* Ag1 = enc + ((size_t)ord[g1 / P_] * P_ + (g1 % P_)) * ENC_ + ak1;
    const ushort_t* Bg0 = WeaT + (size_t)(n0 + ar0) * ENC_ + ak0;
    const ushort_t* Bg1 = WeaT + (size_t)(n0 + ar1) * ENC_ + ak1;
    const int ao0 = ar0 * 40 + ak0, ao1 = ar1 * 40 + ak1;

    const int wm = (wave >> 1) * 64, wn = (wave & 1) * 64;
    f32x4 acc[4][4] = {};

    {
        float4 v0 = *reinterpret_cast<const float4*>(Ag0);
        float4 v1 = *reinterpret_cast<const float4*>(Ag0 + 4);
        float4 v2 = *reinterpret_cast<const float4*>(Ag1);
        float4 v3 = *reinterpret_cast<const float4*>(Ag1 + 4);
        uint4 pa0, pa1;
        pa0.x = f2bf2(v0.x, v0.y); pa0.y = f2bf2(v0.z, v0.w);
        pa0.z = f2bf2(v1.x, v1.y); pa0.w = f2bf2(v1.z, v1.w);
        pa1.x = f2bf2(v2.x, v2.y); pa1.y = f2bf2(v2.z, v2.w);
        pa1.z = f2bf2(v3.x, v3.y); pa1.w = f2bf2(v3.z, v3.w);
        *reinterpret_cast<uint4*>(&As[0][ao0]) = pa0;
        *reinterpret_cast<uint4*>(&As[0][ao1]) = pa1;
        *reinterpret_cast<uint4*>(&Bs[0][ao0]) = *reinterpret_cast<const uint4*>(Bg0);
        *reinterpret_cast<uint4*>(&Bs[0][ao1]) = *reinterpret_cast<const uint4*>(Bg1);
    }
    __syncthreads();

    for (int it = 0; it < 64; ++it) {
        const int cur = it & 1;
        uint4 npa0, npa1, npb0, npb1;
        const bool more = (it < 63);
        if (more) {
            const int k0 = (it + 1) * 32;
            float4 v0 = *reinterpret_cast<const float4*>(Ag0 + k0);
            float4 v1 = *reinterpret_cast<const float4*>(Ag0 + k0 + 4);
            float4 v2 = *reinterpret_cast<const float4*>(Ag1 + k0);
            float4 v3 = *reinterpret_cast<const float4*>(Ag1 + k0 + 4);
            npa0.x = f2bf2(v0.x, v0.y); npa0.y = f2bf2(v0.z, v0.w);
            npa0.z = f2bf2(v1.x, v1.y); npa0.w = f2bf2(v1.z, v1.w);
            npa1.x = f2bf2(v2.x, v2.y); npa1.y = f2bf2(v2.z, v2.w);
            npa1.z = f2bf2(v3.x, v3.y); npa1.w = f2bf2(v3.z, v3.w);
            npb0 = *reinterpret_cast<const uint4*>(Bg0 + k0);
            npb1 = *reinterpret_cast<const uint4*>(Bg1 + k0);
        }
        {
            bf16x8 af[4], bfr[4];
            const int arow = wm + (lane & 15);
            const int brow = wn + (lane & 15);
            const int koff = (lane >> 4) * 8;
#pragma unroll
            for (int mt = 0; mt < 4; ++mt)
                af[mt] = *reinterpret_cast<const bf16x8*>(&As[cur][(arow + mt * 16) * 40 + koff]);
#pragma unroll
            for (int nt = 0; nt < 4; ++nt)
                bfr[nt] = *reinterpret_cast<const bf16x8*>(&Bs[cur][(brow + nt * 16) * 40 + koff]);
#pragma unroll
            for (int mt = 0; mt < 4; ++mt)
#pragma unroll
                for (int nt = 0; nt < 4; ++nt)
                    acc[mt][nt] = __builtin_amdgcn_mfma_f32_16x16x32_bf16(
                        af[mt], bfr[nt], acc[mt][nt], 0, 0, 0);
        }
        if (more) {
            const int nxt = cur ^ 1;
            *reinterpret_cast<uint4*>(&As[nxt][ao0]) = npa0;
            *reinterpret_cast<uint4*>(&As[nxt][ao1]) = npa1;
            *reinterpret_cast<uint4*>(&Bs[nxt][ao0]) = npb0;
            *reinterpret_cast<uint4*>(&Bs[nxt][ao1]) = npb1;
        }
        __syncthreads();
    }
    const int rbase = (lane >> 4) * 4;
    const int cbase = lane & 15;
#pragma unroll
    for (int nt = 0; nt < 4; ++nt) {
        int col = n0 + wn + nt * 16 + cbase;
        float be = bea[col];
#pragma unroll
        for (int mt = 0; mt < 4; ++mt) {
            int row = m0 + wm + mt * 16 + rbase;
#pragma unroll
            for (int r = 0; r < 4; ++r)
                a1b[(size_t)(row + r) * 512 + col] = f2bf(acc[mt][nt][r] + be);
        }
    }
}

// ============ prepack Wz = [Wl ; Ul] (K=3072, N=2048) into MFMA B-fragment layout ============
// pack idx = ((nt*96 + kt)*64 + lane)*8 ushorts; element (lane,j) = W[kt*32+(lane>>4)*8+j][nt*16+(lane&15)]
__global__ void k_packWz(const float* __restrict__ Wl, const float* __restrict__ Ul,
                         ushort_t* __restrict__ Wz)
{
    const unsigned tidg = blockIdx.x * 256 + threadIdx.x;    // 786432 total, exact
    const int l = tidg & 63;
    const unsigned rem = tidg >> 6;
    const int kt = rem % 96;
    const int nt = rem / 96;
    const int k = kt * 32 + ((l >> 4) << 3);
    const int n = nt * 16 + (l & 15);
    float v[8];
#pragma unroll
    for (int j = 0; j < 8; ++j) {
        int kr = k + j;
        v[j] = (kr < 2560) ? Wl[(size_t)kr * 2048 + n] : Ul[(size_t)(kr - 2560) * 2048 + n];
    }
    uint4 o;
    o.x = f2bf2(v[0], v[1]); o.y = f2bf2(v[2], v[3]);
    o.z = f2bf2(v[4], v[5]); o.w = f2bf2(v[6], v[7]);
    *reinterpret_cast<uint4*>(Wz + (size_t)tidg * 8) = o;
}

// ============ prepack Wc = [Wb | Wga | Wo | 0-pad] (K=512, N=12672) ============
// pack idx = ((nt*16 + kt)*64 + lane)*8 ushorts
__global__ void k_packWc(const float* __restrict__ Wb, const float* __restrict__ Wga,
                         const float* __restrict__ Wo, ushort_t* __restrict__ Wc)
{
    const unsigned tidg = blockIdx.x * 256 + threadIdx.x;    // 811008 total, exact
    const int l = tidg & 63;
    const int kt = (tidg >> 6) & 15;
    const int nt = tidg >> 10;
    const int k = kt * 32 + ((l >> 4) << 3);
    const int n = nt * 16 + (l & 15);
    float v[8];
#pragma unroll
    for (int j = 0; j < 8; ++j) {
        int kr = k + j;
        float x;
        if (n < 2048)            x = Wb[(size_t)kr * 2048 + n];
        else if (n < 2560)       x = Wga[(size_t)kr * 512 + (n - 2048)];
        else if (n < 2560 + V_)  x = Wo[(size_t)kr * V_ + (n - 2560)];
        else                     x = 0.f;
        v[j] = x;
    }
    uint4 o;
    o.x = f2bf2(v[0], v[1]); o.y = f2bf2(v[2], v[3]);
    o.z = f2bf2(v[4], v[5]); o.w = f2bf2(v[6], v[7]);
    *reinterpret_cast<uint4*>(Wc + (size_t)tidg * 8) = o;
}

// ============ e kernel: 128 blocks (b x 4 p-chunks of 49) ============
__global__ __launch_bounds__(256, 1) void k_e(
    const float* __restrict__ a2s, const float* __restrict__ Wfa,
    const float* __restrict__ bfa, const ushort_t* __restrict__ a1b,
    float* __restrict__ eshW)
{
    __shared__ float a2sh[512];
    __shared__ float wfsh[512];
    const int b = blockIdx.x >> 2, pc = blockIdx.x & 3;
    const int tid = threadIdx.x;
    const int wave = tid >> 6, lane = tid & 63;
    a2sh[tid] = a2s[b * 512 + tid];       a2sh[tid + 256] = a2s[b * 512 + 256 + tid];
    wfsh[tid] = Wfa[tid];                 wfsh[tid + 256] = Wfa[256 + tid];
    __syncthreads();

    const int grp = lane >> 4, sub = lane & 15;
    float4 a2r[4][2], wfr[4][2];
#pragma unroll
    for (int blk = 0; blk < 4; ++blk)
#pragma unroll
        for (int j = 0; j < 2; ++j) {
            int d = blk * 128 + sub * 8 + j * 4;
            a2r[blk][j] = *reinterpret_cast<const float4*>(&a2sh[d]);
            wfr[blk][j] = *reinterpret_cast<const float4*>(&wfsh[d]);
        }
    const float bf0 = bfa[0];
    const int p0 = pc * 49;
#pragma unroll
    for (int pass = 0; pass < 4; ++pass) {
        const int pl = pass * 16 + wave * 4 + grp;
        const bool valid = pl < 49;
        const int p = p0 + (valid ? pl : 0);
        const ushort_t* arow = a1b + ((size_t)b * P_ + p) * 512;
        float s = 0.f;
#pragma unroll
        for (int blk = 0; blk < 4; ++blk) {
            uint4 raw = *reinterpret_cast<const uint4*>(arow + blk * 128 + sub * 8);
            float4 av = a2r[blk][0], wv = wfr[blk][0];
            float v;
            v = bfu_lo(raw.x) + av.x; v = v > 0.f ? v : 0.f; s += v * wv.x;
            v = bfu_hi(raw.x) + av.y; v = v > 0.f ? v : 0.f; s += v * wv.y;
            v = bfu_lo(raw.y) + av.z; v = v > 0.f ? v : 0.f; s += v * wv.z;
            v = bfu_hi(raw.y) + av.w; v = v > 0.f ? v : 0.f; s += v * wv.w;
            av = a2r[blk][1]; wv = wfr[blk][1];
            v = bfu_lo(raw.z) + av.x; v = v > 0.f ? v : 0.f; s += v * wv.x;
            v = bfu_hi(raw.z) + av.y; v = v > 0.f ? v : 0.f; s += v * wv.y;
            v = bfu_lo(raw.w) + av.z; v = v > 0.f ? v : 0.f; s += v * wv.z;
            v = bfu_hi(raw.w) + av.w; v = v > 0.f ? v : 0.f; s += v * wv.w;
        }
        s += __shfl_xor(s, 1, 64);
        s += __shfl_xor(s, 2, 64);
        s += __shfl_xor(s, 4, 64);
        s += __shfl_xor(s, 8, 64);
        if (sub == 0 && valid) eshW[b * 256 + p0 + pl] = s + bf0;
    }
}

// ============ fused softmax + awe + beta-gate + x-write (+out_alpha): 128 blocks ============
__global__ __launch_bounds__(256, 1) void k_awex(
    const float* __restrict__ eshW, const float* __restrict__ enc,
    const int* __restrict__ ord, const int* __restrict__ slen, int t,
    const float* __restrict__ beta, float* __restrict__ out_alpha,
    ushort_t* __restrict__ XB)
{
    __shared__ float red[256];
    __shared__ float alsh[P_];
    const int b = blockIdx.x >> 2, ec = blockIdx.x & 3;
    const int tid = threadIdx.x;

    float v = (tid < P_) ? eshW[b * 256 + tid] : -1e30f;
    red[tid] = v; __syncthreads();
    for (int s2 = 128; s2 > 0; s2 >>= 1) {
        if (tid < s2) red[tid] = fmaxf(red[tid], red[tid + s2]);
        __syncthreads();
    }
    float mx = red[0]; __syncthreads();
    float ex = (tid < P_) ? expf(v - mx) : 0.f;
    red[tid] = ex; __syncthreads();
    for (int s2 = 128; s2 > 0; s2 >>= 1) {
        if (tid < s2) red[tid] += red[tid + s2];
        __syncthreads();
    }
    float inv = 1.0f / red[0];
    float al = ex * inv;
    if (tid < P_) alsh[tid] = al;
    if (ec == 0 && tid < P_) {
        float mf = (slen[b] > t) ? 1.f : 0.f;
        out_alpha[((size_t)b * STEPS + t) * P_ + tid] = al * mf;
    }
    __syncthreads();

    // awe for 2 columns per thread
    const int e0 = ec * 512 + tid * 2;
    const float* ep = enc + (size_t)ord[b] * (P_ * ENC_) + e0;
    float s0 = 0.f, s1 = 0.f;
    for (int p = 0; p < P_; ++p) {
        float2 u = *reinterpret_cast<const float2*>(ep + (size_t)p * ENC_);
        float ap = alsh[p];
        s0 += ap * u.x; s1 += ap * u.y;
    }
    float2 bt = *reinterpret_cast<const float2*>(&beta[b * 2048 + e0]);
    unsigned pk = f2bf2(s0 * bt.x, s1 * bt.y);
    *reinterpret_cast<unsigned*>(XB + (size_t)b * XW_ + 512 + e0) = pk;
}

// ============ GEMM1 (MFMA): z partials = XB(32x3072) @ WzPack, grid (32 nt-groups, 4 kc) ============
__global__ __launch_bounds__(256) void k_zmfma(const ushort_t* __restrict__ XB,
                                               const ushort_t* __restrict__ WzP,
                                               float* __restrict__ pz4)
{
    const int tid = threadIdx.x, lane = tid & 63, w = tid >> 6;
    const int nt = blockIdx.x * 4 + w;          // 0..127
    const int kt0 = blockIdx.y * 24;            // 4 chunks of 768 k
    const int ar = lane & 15, ak = (lane >> 4) * 8;
    const ushort_t* A0 = XB + (size_t)ar * XW_ + kt0 * 32 + ak;
    const ushort_t* Bp = WzP + ((size_t)nt * 96 + kt0) * 512 + lane * 8;
    f32x4 acc0 = {}, acc1 = {};
    for (int kt = 0; kt < 24; ++kt) {
        bf16x8 a0 = *reinterpret_cast<const bf16x8*>(A0 + kt * 32);
        bf16x8 a1 = *reinterpret_cast<const bf16x8*>(A0 + 16 * XW_ + kt * 32);
        bf16x8 bf = *reinterpret_cast<const bf16x8*>(Bp + kt * 512);
        acc0 = __builtin_amdgcn_mfma_f32_16x16x32_bf16(a0, bf, acc0, 0, 0, 0);
        acc1 = __builtin_amdgcn_mfma_f32_16x16x32_bf16(a1, bf, acc1, 0, 0, 0);
    }
    const int col = nt * 16 + (lane & 15);
    const int r0 = (lane >> 4) * 4;
    float* po = pz4 + (size_t)blockIdx.y * 65536 + col;
#pragma unroll
    for (int r = 0; r < 4; ++r) {
        po[(size_t)(r0 + r) * 2048] = acc0[r];
        po[(size_t)(16 + r0 + r) * 2048] = acc1[r];
    }
}

// ============ gates: sum 4 z-partials, LSTM cell, write c fp32 + cB bf16 + h into XB ============
__global__ void k_gates(const float* __restrict__ pz4, const float* __restrict__ bl,
                        const float* __restrict__ c_in, const int* __restrict__ slen, int t,
                        float* __restrict__ c_out, ushort_t* __restrict__ cB,
                        ushort_t* __restrict__ XB)
{
    int tid = blockIdx.x * 256 + threadIdx.x;
    int b = tid >> 9, l = tid & 511;
    float zi = 0.f, zf = 0.f, zg = 0.f, zo = 0.f;
#pragma unroll
    for (int kc = 0; kc < 4; ++kc) {
        const float* row = pz4 + (size_t)kc * 65536 + b * 2048;
        zi += row[l]; zf += row[512 + l]; zg += row[1024 + l]; zo += row[1536 + l];
    }
    zi += bl[l]; zf += bl[512 + l]; zg += bl[1024 + l]; zo += bl[1536 + l];
    float si = 1.f / (1.f + expf(-zi));
    float sf = 1.f / (1.f + expf(-zf));
    float so = 1.f / (1.f + expf(-zo));
    float g  = tanhf(zg);
    float cn = sf * c_in[tid] + si * g;
    float hn = so * tanhf(cn);
    float mf = (slen[b] > t) ? 1.f : 0.f;
    cn *= mf; hn *= mf;
    c_out[tid] = cn;
    cB[tid] = f2bf(cn);
    XB[(size_t)b * XW_ + 2560 + l] = f2bf(hn);
}

// ============ GEMM2 (MFMA): cB(32x512) @ [Wb|Wga|Wo]Pack, epilogue writes beta/a2s/pred ============
// bids 0..98: GEMM n-panels of 128; bids 99..100: emb gather for tnext
__global__ __launch_bounds__(256) void k_cmfma(
    const ushort_t* __restrict__ cB, const ushort_t* __restrict__ WcP,
    const float* __restrict__ bb, const float* __restrict__ bga, const float* __restrict__ bo,
    const int* __restrict__ slen, int t, int do_pred, int tnext,
    const int* __restrict__ seqs, const float* __restrict__ emb, const int* __restrict__ ord,
    float* __restrict__ beta, float* __restrict__ a2s, float* __restrict__ out_pred,
    ushort_t* __restrict__ XB)
{
    const int bid = blockIdx.x, tid = threadIdx.x;
    if (bid >= 99) {
        const int g = (bid - 99) * 256 + tid;    // 0..511
        const int b = g >> 4, j0 = (g & 15) * 32;
        const int tok = seqs[ord[b] * T_ + tnext];
        const float4* src = reinterpret_cast<const float4*>(emb + (size_t)tok * E_ + j0);
        uint4* dst = reinterpret_cast<uint4*>(XB + (size_t)b * XW_ + j0);
#pragma unroll
        for (int q = 0; q < 4; ++q) {
            float4 v0 = src[2 * q], v1 = src[2 * q + 1];
            uint4 o;
            o.x = f2bf2(v0.x, v0.y); o.y = f2bf2(v0.z, v0.w);
            o.z = f2bf2(v1.x, v1.y); o.w = f2bf2(v1.z, v1.w);
            dst[q] = o;
        }
        return;
    }
    const int lane = tid & 63, w = tid >> 6;
    const int nt0 = bid * 8 + w * 2;                 // two 16-col tiles per wave
    const int ar = lane & 15, ak = (lane >> 4) * 8;
    const ushort_t* A0 = cB + ar * 512 + ak;
    const ushort_t* Bp = WcP + (size_t)nt0 * 8192 + lane * 8;
    f32x4 acc[2][2] = {};
    for (int kt = 0; kt < 16; ++kt) {
        bf16x8 a0 = *reinterpret_cast<const bf16x8*>(A0 + kt * 32);
        bf16x8 a1 = *reinterpret_cast<const bf16x8*>(A0 + 16 * 512 + kt * 32);
        bf16x8 b0 = *reinterpret_cast<const bf16x8*>(Bp + kt * 512);
        bf16x8 b1 = *reinterpret_cast<const bf16x8*>(Bp + 8192 + kt * 512);
        acc[0][0] = __builtin_amdgcn_mfma_f32_16x16x32_bf16(a0, b0, acc[0][0], 0, 0, 0);
        acc[0][1] = __builtin_amdgcn_mfma_f32_16x16x32_bf16(a0, b1, acc[0][1], 0, 0, 0);
        acc[1][0] = __builtin_amdgcn_mfma_f32_16x16x32_bf16(a1, b0, acc[1][0], 0, 0, 0);
        acc[1][1] = __builtin_amdgcn_mfma_f32_16x16x32_bf16(a1, b1, acc[1][1], 0, 0, 0);
    }
    const int r0 = (lane >> 4) * 4, cb = lane & 15;
#pragma unroll
    for (int nti = 0; nti < 2; ++nti) {
        const int n = (nt0 + nti) * 16 + cb;
#pragma unroll
        for (int mt = 0; mt < 2; ++mt) {
#pragma unroll
            for (int r = 0; r < 4; ++r) {
                const int brow = mt * 16 + r0 + r;
                float v = acc[mt][nti][r];
                if (n < 2048) {
                    beta[brow * 2048 + n] = 1.f / (1.f + expf(-(v + bb[n])));
                } else if (n < 2560) {
                    a2s[brow * 512 + (n - 2048)] = v + bga[n - 2048];
                } else if (n < 2560 + V_) {
                    if (do_pred) {
                        float mf = (slen[brow] > t) ? 1.f : 0.f;
                        out_pred[((size_t)brow * STEPS + t) * V_ + (n - 2560)] =
                            (v + bo[n - 2560]) * mf;
                    }
                }
            }
        }
    }
}

extern "C" void kernel_launch(void* const* d_in, const int* in_sizes, int n_in,
                              void* d_out, int out_size, void* d_ws, size_t ws_size,
                              hipStream_t stream)
{
    const float* enc  = (const float*)d_in[0];
    const int*   seqs = (const int*)  d_in[1];
    const float* emb  = (const float*)d_in[2];
    const float* Wea  = (const float*)d_in[3];
    const float* bea  = (const float*)d_in[4];
    const float* Wga  = (const float*)d_in[5];
    const float* bga  = (const float*)d_in[6];
    const float* Wfa  = (const float*)d_in[7];
    const float* bfa  = (const float*)d_in[8];
    const float* Wl   = (const float*)d_in[9];
    const float* Ul   = (const float*)d_in[10];
    const float* bl   = (const float*)d_in[11];
    const float* Wim  = (const float*)d_in[12];
    const float* bim  = (const float*)d_in[13];
    const float* Wic  = (const float*)d_in[14];
    const float* bic  = (const float*)d_in[15];
    const float* Wb   = (const float*)d_in[16];
    const float* bb   = (const float*)d_in[17];
    const float* Wo   = (const float*)d_in[18];
    const float* bo   = (const float*)d_in[19];

    float* out = (float*)d_out;
    float* ws  = (float*)d_ws;
    int* ord  = (int*)(ws + WS_ORD);
    int* slen = (int*)(ws + WS_SLEN);
    ushort_t* cBu  = (ushort_t*)(ws + WS_CB);
    ushort_t* XB   = (ushort_t*)(ws + WS_XB);
    ushort_t* a1b  = (ushort_t*)(ws + WS_A1B);
    ushort_t* WzP  = (ushort_t*)(ws + WS_WZP);
    ushort_t* WcP  = (ushort_t*)(ws + WS_WCP);
    ushort_t* WeaT = (ushort_t*)(ws + WS_WEAT);
    float* a2s  = ws + WS_A2S;
    float* eshW = ws + WS_ESH;
    float* beta = ws + WS_BETA;
    float* pz4  = ws + WS_PZ4;

    // ---- prologue ----
    k_order<<<1, 64, 0, stream>>>(seqs, ord, slen, out + OUT_ORDER);
    k_mean<<<256, 256, 0, stream>>>(enc, ord, ws + WS_MEAN);
    sg_partial<<<dim3(2, 16, 2), 256, 0, stream>>>(ws + WS_MEAN, Wim, ws + WS_PH, 2048, 512, 128, 0);
    sg_partial<<<dim3(2, 16, 2), 256, 0, stream>>>(ws + WS_MEAN, Wic, ws + WS_PH, 2048, 512, 128, 16);
    k_h0c0<<<128, 256, 0, stream>>>(ws + WS_PH, bim, bic, ws + WS_CBUF, cBu, XB);
    k_castWT<<<4096, 256, 0, stream>>>(Wea, WeaT);
    k_a1_mfma<<<dim3(49, 4), 256, 0, stream>>>(enc, WeaT, bea, ord, a1b);
    k_packWz<<<3072, 256, 0, stream>>>(Wl, Ul, WzP);
    k_packWc<<<3168, 256, 0, stream>>>(Wb, Wga, Wo, WcP);
    // prep for step 0: beta, a2s, emb(0) from c0/h0; pred disabled
    k_cmfma<<<101, 256, 0, stream>>>(cBu, WcP, bb, bga, bo, slen, 0, 0, 0,
                                     seqs, emb, ord, beta, a2s, out + OUT_PRED, XB);

    // ---- decode steps ----
    for (int t = 0; t < STEPS; ++t) {
        float* c_in  = ws + WS_CBUF + (t & 1) * (B_ * L_);
        float* c_out = ws + WS_CBUF + ((t + 1) & 1) * (B_ * L_);

        k_e<<<128, 256, 0, stream>>>(a2s, Wfa, bfa, a1b, eshW);
        k_awex<<<128, 256, 0, stream>>>(eshW, enc, ord, slen, t, beta, out + OUT_ALPHA, XB);
        k_zmfma<<<dim3(32, 4), 256, 0, stream>>>(XB, WzP, pz4);
        k_gates<<<64, 256, 0, stream>>>(pz4, bl, c_in, slen, t, c_out, cBu, XB);
        k_cmfma<<<101, 256, 0, stream>>>(cBu, WcP, bb, bga, bo, slen, t, 1, t + 1,
                                         seqs, emb, ord, beta, a2s, out + OUT_PRED, XB);
    }
}